// Round 10
// baseline (340.132 us; speedup 1.0000x reference)
//
#include <hip/hip_runtime.h>
#include <math.h>

#define NF        128
#define H_DIM     256
#define NA        200
#define B_SAMPLES 512
#define ALPHA_LR  0.01f
#define B_MIN_C   1e-4f

#define NTHREADS  256               // 4 waves: thread t owns full row t (t<200)
#define ROWS_PER_WAVE 50            // exact-path: 4 waves x 50 rows

#define N_PH1     10
#define N_REFINE  1
#define CG_MAX    32
#define TOL2_LO   4e-4f             // refinement CG tolerance (accuracy anchor)
#define TOL2_P1   4e-3f             // phase-1 CG tolerance floor
#define TOL2_HI   6e-2f             // phase-1 CG tolerance cap
#define P1_FACT   8.f               // adaptive factor
#define P1_EXIT   1e-7f             // phase-1 Newton early-exit

typedef _Float16 h2_t __attribute__((ext_vector_type(2)));
typedef unsigned uv4  __attribute__((ext_vector_type(4)));

__device__ __forceinline__ h2_t as_h2(unsigned u){
  union { unsigned u; h2_t h; } c; c.u = u; return c.h;
}
__device__ __forceinline__ unsigned pk_f16(float a, float b){
#if __has_builtin(__builtin_amdgcn_cvt_pkrtz)
  union { decltype(__builtin_amdgcn_cvt_pkrtz(0.f, 0.f)) h; unsigned u; } c;
  c.h = __builtin_amdgcn_cvt_pkrtz(a, b);
  return c.u;
#else
  union { h2_t h; unsigned u; } c;
  c.h = (h2_t){ (_Float16)a, (_Float16)b };
  return c.u;
#endif
}
__device__ __forceinline__ float fdot2(unsigned m, unsigned v, float acc){
#if __has_builtin(__builtin_amdgcn_fdot2)
  return __builtin_amdgcn_fdot2(as_h2(m), as_h2(v), acc, false);
#else
  h2_t a = as_h2(m), b = as_h2(v);
  return fmaf((float)a.y, (float)b.y, fmaf((float)a.x, (float)b.x, acc));
#endif
}
// fast reciprocal (v_rcp_f32, ~1e-7 rel) for loop-carried scalar chain
__device__ __forceinline__ float fast_rcp(float x){
#if __has_builtin(__builtin_amdgcn_rcpf)
  return __builtin_amdgcn_rcpf(x);
#else
  return 1.f / x;
#endif
}

// ---------------- DPP wave-64 reductions (result valid in lane 63) --------
__device__ __forceinline__ float dpp_wave_sum(float v){
  v += __int_as_float(__builtin_amdgcn_update_dpp(0, __float_as_int(v), 0x111, 0xf, 0xf, false));
  v += __int_as_float(__builtin_amdgcn_update_dpp(0, __float_as_int(v), 0x112, 0xf, 0xf, false));
  v += __int_as_float(__builtin_amdgcn_update_dpp(0, __float_as_int(v), 0x114, 0xf, 0xf, false));
  v += __int_as_float(__builtin_amdgcn_update_dpp(0, __float_as_int(v), 0x118, 0xf, 0xf, false));
  v += __int_as_float(__builtin_amdgcn_update_dpp(0, __float_as_int(v), 0x142, 0xa, 0xf, false));
  v += __int_as_float(__builtin_amdgcn_update_dpp(0, __float_as_int(v), 0x143, 0xc, 0xf, false));
  return v;
}
__device__ __forceinline__ float dpp_wave_min(float v){
  const int PINF = 0x7f800000;
  v = fminf(v, __int_as_float(__builtin_amdgcn_update_dpp(PINF, __float_as_int(v), 0x111, 0xf, 0xf, false)));
  v = fminf(v, __int_as_float(__builtin_amdgcn_update_dpp(PINF, __float_as_int(v), 0x112, 0xf, 0xf, false)));
  v = fminf(v, __int_as_float(__builtin_amdgcn_update_dpp(PINF, __float_as_int(v), 0x114, 0xf, 0xf, false)));
  v = fminf(v, __int_as_float(__builtin_amdgcn_update_dpp(PINF, __float_as_int(v), 0x118, 0xf, 0xf, false)));
  v = fminf(v, __int_as_float(__builtin_amdgcn_update_dpp(PINF, __float_as_int(v), 0x142, 0xa, 0xf, false)));
  v = fminf(v, __int_as_float(__builtin_amdgcn_update_dpp(PINF, __float_as_int(v), 0x143, 0xc, 0xf, false)));
  return v;
}
__device__ __forceinline__ float dpp_wave_max(float v){
  const int NINF = 0xff800000;
  v = fmaxf(v, __int_as_float(__builtin_amdgcn_update_dpp(NINF, __float_as_int(v), 0x111, 0xf, 0xf, false)));
  v = fmaxf(v, __int_as_float(__builtin_amdgcn_update_dpp(NINF, __float_as_int(v), 0x112, 0xf, 0xf, false)));
  v = fmaxf(v, __int_as_float(__builtin_amdgcn_update_dpp(NINF, __float_as_int(v), 0x114, 0xf, 0xf, false)));
  v = fmaxf(v, __int_as_float(__builtin_amdgcn_update_dpp(NINF, __float_as_int(v), 0x118, 0xf, 0xf, false)));
  v = fmaxf(v, __int_as_float(__builtin_amdgcn_update_dpp(NINF, __float_as_int(v), 0x142, 0xa, 0xf, false)));
  v = fmaxf(v, __int_as_float(__builtin_amdgcn_update_dpp(NINF, __float_as_int(v), 0x143, 0xc, 0xf, false)));
  return v;
}
// block reductions over 4 waves (prologue only)
__device__ __forceinline__ float block_sum4(float v, float* red, int tid){
  __syncthreads();
  v = dpp_wave_sum(v);
  if ((tid & 63) == 63) red[tid >> 6] = v;
  __syncthreads();
  return (red[0] + red[1]) + (red[2] + red[3]);
}
__device__ __forceinline__ float block_max4(float v, float* red, int tid){
  __syncthreads();
  v = dpp_wave_max(v);
  if ((tid & 63) == 63) red[tid >> 6] = v;
  __syncthreads();
  return fmaxf(fmaxf(red[0], red[1]), fmaxf(red[2], red[3]));
}

// owner writes its f16 vector entry (rows 0..199 contiguous)
__device__ __forceinline__ void put_ph(unsigned short* phs, int row, float v){
  phs[row] = (unsigned short)(pk_f16(v, 0.f) & 0xffffu);
}

// packed-f16 full-row matvec: 100 dwords from VGPRs.
// Prefetch ALL 25 p-quads first (one LDS-latency exposure, not five).
__device__ __forceinline__ float mv_dot2(const unsigned* mreg,
                                         const unsigned* __restrict__ ph){
  const uv4* v4 = (const uv4*)ph;
  uv4 pv[25];
  #pragma unroll
  for (int k = 0; k < 25; ++k) pv[k] = v4[k];
  float a0=0.f, a1=0.f, a2=0.f, a3=0.f;
  #pragma unroll
  for (int k = 0; k < 25; ++k){
    a0 = fdot2(mreg[4*k+0], pv[k].x, a0);
    a1 = fdot2(mreg[4*k+1], pv[k].y, a1);
    a2 = fdot2(mreg[4*k+2], pv[k].z, a2);
    a3 = fdot2(mreg[4*k+3], pv[k].w, a3);
  }
  return (a0 + a1) + (a2 + a3);
}

// f16-matrix x fp32-vector (phase-1 gradient: exact fixed point of f16 system)
__device__ __forceinline__ float mv_f32v(const unsigned* mreg,
                                         const float* __restrict__ vv){
  const float4* v4 = (const float4*)vv;
  float a0=0.f, a1=0.f, a2=0.f, a3=0.f;
  #pragma unroll
  for (int k = 0; k < 25; ++k){
    float4 va = v4[2*k], vb = v4[2*k+1];
    h2_t m0 = as_h2(mreg[4*k+0]), m1 = as_h2(mreg[4*k+1]);
    h2_t m2 = as_h2(mreg[4*k+2]), m3 = as_h2(mreg[4*k+3]);
    a0 = fmaf((float)m0.x, va.x, a0); a1 = fmaf((float)m0.y, va.y, a1);
    a2 = fmaf((float)m1.x, va.z, a2); a3 = fmaf((float)m1.y, va.w, a3);
    a0 = fmaf((float)m2.x, vb.x, a0); a1 = fmaf((float)m2.y, vb.y, a1);
    a2 = fmaf((float)m3.x, vb.z, a2); a3 = fmaf((float)m3.y, vb.w, a3);
  }
  return (a0 + a1) + (a2 + a3);
}

// NO 2nd launch_bounds arg (R8: "(256,2)" clamps to 128 VGPR -> spill).
extern "C" __global__ __launch_bounds__(NTHREADS)
void rb_kernel(const float* __restrict__ x,  const float* __restrict__ Sigma,
               const float* __restrict__ W1, const float* __restrict__ b1,
               const float* __restrict__ W2, const float* __restrict__ b2,
               float* __restrict__ out) {
  __shared__ __align__(16) unsigned ph[100];          // packed f16 vector (200 h)
  __shared__ __align__(16) float yv[NA];
  __shared__ __align__(16) float partial[NA];
  __shared__ float xs[NF];
  __shared__ float hs[H_DIM];
  __shared__ __align__(16) float4 red4[4];            // fused CG reduction slots
  __shared__ float redD[4], red8[4];

  const int tid  = threadIdx.x;
  const int s    = blockIdx.x;
  const bool act = tid < NA;                          // thread t owns row t
  const int row  = tid;
  const float* S = Sigma + (size_t)s * NA * NA;
  unsigned short* phs = (unsigned short*)ph;

  if (tid < NF) xs[tid] = x[s * NF + tid];
  float sd = act ? S[(size_t)row * NA + row] : 0.f;

  // ---- stage Sigma row (packed f16): 100 dwords -> VGPRs ----
  unsigned mreg[100];
  if (act){
    const float4* rowp = (const float4*)(S + (size_t)row * NA);
    #pragma unroll
    for (int k = 0; k < 50; ++k){
      float4 w = rowp[k];
      mreg[2*k]   = pk_f16(w.x, w.y);
      mreg[2*k+1] = pk_f16(w.z, w.w);
    }
  }

  // ---- MLP ----
  __syncthreads();                        // xs visible
  {
    const float* w = W1 + tid * NF;       // tid < 256 == H_DIM
    float acc = b1[tid];
    #pragma unroll 8
    for (int j = 0; j < NF; ++j) acc = fmaf(w[j], xs[j], acc);
    hs[tid] = (acc >= 0.f) ? acc : ALPHA_LR * acc;
  }
  __syncthreads();
  float logit = -INFINITY;
  if (act){
    const float* w = W2 + row * H_DIM;
    float acc = b2[row];
    #pragma unroll 8
    for (int j = 0; j < H_DIM; ++j) acc = fmaf(w[j], hs[j], acc);
    logit = acc;
  }

  // ---- softmax -> b (output 2); clamp+renorm -> b_ (local, row==tid) ----
  float mx = block_max4(logit, red8, tid);
  float e  = act ? expf(logit - mx) : 0.f;
  float es = block_sum4(e, red8, tid);
  float bsoft = e / es;
  if (act) out[(size_t)B_SAMPLES * NA + (size_t)s * NA + row] = bsoft;
  float bcl = fmaxf(bsoft, B_MIN_C);
  float bs  = block_sum4(act ? bcl : 0.f, red8, tid);

  float b_ = 0.f, y = 0.f;
  // R10: scale-matched init direction u_i = sqrt(b_i / S_ii). The fixed
  // point satisfies y_i (S y)_i = b_i, so u matches per-coordinate scale
  // (the old u=b was off by ~sqrt(b_max/b_min) per coord for concentrated
  // b — the slow-tail samples). Phase-1 path is free: the exact-gradient
  // refinement pins the endpoint.
  float u0 = 0.f;
  if (act){
    b_ = bcl / bs;
    u0 = sqrtf(b_ * fast_rcp(sd));
    put_ph(phs, row, u0);
  }

  // ---- y0 = u / sqrt(u^T S u) (optimal scaling of direction u) ----
  __syncthreads();                               // ph visible
  {
    float acc = act ? mv_dot2(mreg, ph) : 0.f;
    float wq  = dpp_wave_sum(act ? u0 * acc : 0.f);
    if ((tid & 63) == 63) red4[tid >> 6] = make_float4(wq, 0.f, 0.f, 0.f);
    __syncthreads();
    float quad = (red4[0].x + red4[1].x) + (red4[2].x + red4[3].x);
    if (act){ y = u0 / sqrtf(quad); yv[row] = y; }
  }

  // ---- damped inexact Newton ----
  float gg0 = 1.f;
  bool  ph1done = false;
  int   nexact  = 0;
  for (int it = 0; it < N_PH1 + N_REFINE; ++it){
    if (nexact >= N_REFINE) break;
    const bool exact = ph1done;
    if (exact) ++nexact;

    // --- gradient matvec q = (S y)_row (fp32 y, f16 or exact matrix) ---
    float q = 0.f;
    if (exact){
      __syncthreads();                           // yv visible, partial free
      int lane = tid & 63, wid = tid >> 6;
      int r0 = wid * ROWS_PER_WAVE;
      for (int rr = r0; rr < r0 + ROWS_PER_WAVE; ++rr){
        const float* rowp = S + (size_t)rr * NA;
        float a = rowp[lane]*yv[lane] + rowp[lane+64]*yv[lane+64]
                + rowp[lane+128]*yv[lane+128];
        if (lane < NA - 192) a += rowp[lane+192]*yv[lane+192];
        a = dpp_wave_sum(a);
        if (lane == 63) partial[rr] = a;
      }
      __syncthreads();
      if (act) q = partial[row];
    } else {
      __syncthreads();                           // yv visible
      q = act ? mv_f32v(mreg, yv) : 0.f;
    }

    // --- Newton init; reduce gg and rz together ---
    float g=0.f, d=0.f, mi=0.f;
    if (act){
      float ry = fast_rcp(y);
      g  = q - b_ * ry;
      d  = b_ * ry * ry;
      mi = fast_rcp(sd + d);
    }
    float wg = dpp_wave_sum(act ? g * g : 0.f);
    float wz = dpp_wave_sum(act ? g * g * mi : 0.f);   // rz = g^T M^-1 g
    if ((tid & 63) == 63) red4[tid >> 6] = make_float4(wg, wz, 0.f, 0.f);
    __syncthreads();
    float4 t0 = red4[0], t1 = red4[1], t2 = red4[2], t3 = red4[3];
    float gg = (t0.x + t1.x) + (t2.x + t3.x);
    float rz = (t0.y + t1.y) + (t2.y + t3.y);
    if (it == 0) gg0 = fmaxf(gg, 1e-30f);
    float tol2 = exact ? TOL2_LO
                       : fminf(TOL2_HI, fmaxf(TOL2_P1, P1_FACT * (gg / gg0)));

    if (gg > 1e-24f){
      // --- scale CG system by 1/||g|| so packed-f16 p never underflows ---
      const float cinv = rsqrtf(gg);
      const float csc  = sqrtf(gg);
      float r=0.f, z=0.f, dy=0.f, pj=0.f;
      if (act){
        r  = -g * cinv;
        z  = mi * r;
        pj = z;
        put_ph(phs, row, pj);
      }
      rz = rz * cinv * cinv;

      // --- Jacobi-PCG, fused single reduction (pq, rq, qq in one float4) ---
      const float rz0 = rz;
      for (int j = 0; j < CG_MAX; ++j){
        __syncthreads();                         // B1: ph visible, red4 reuse safe
        float qp = act ? mv_dot2(mreg, ph) : 0.f;
        float qf=0.f, cpq=0.f, crq=0.f, cqq=0.f;
        if (act){
          qf = qp + d * pj;
          float u = mi * qf;
          cpq = pj * qf; crq = r * u; cqq = qf * u;
        }
        cpq = dpp_wave_sum(cpq); crq = dpp_wave_sum(crq); cqq = dpp_wave_sum(cqq);
        if ((tid & 63) == 63) red4[tid >> 6] = make_float4(cpq, crq, cqq, 0.f);
        __syncthreads();                         // B2
        float4 u0_ = red4[0], u1 = red4[1], u2 = red4[2], u3 = red4[3];
        float pq = (u0_.x + u1.x) + (u2.x + u3.x);
        float rq = (u0_.y + u1.y) + (u2.y + u3.y);
        float qq = (u0_.z + u1.z) + (u2.z + u3.z);
        float alpha = rz * fast_rcp(pq);
        float rznew = fmaxf(fmaf(alpha*alpha, qq, fmaf(-2.f*alpha, rq, rz)), 0.f);
        if (act){
          dy = fmaf(alpha, pj, dy);
          r  = fmaf(-alpha, qf, r);
          z  = mi * r;
        }
        bool brk = (rznew <= tol2 * rz0) || (j == CG_MAX - 1);
        if (!brk){
          float beta = rznew * fast_rcp(rz);
          if (act){ pj = fmaf(beta, pj, z); put_ph(phs, row, pj); }
        }
        rz = rznew;
        if (brk) break;
      }

      // --- unscale dy; damped step keeping y > 0.
      // Phase-1 uses 0.99 fraction-to-boundary (log-barrier tolerates it;
      // faster traversal for concentrated-b tails); exact refinement keeps
      // the reference 0.9. ---
      if (act) dy *= csc;
      float ratio = (act && dy < 0.f) ? (-y / dy) : 1e30f;
      float wmn = dpp_wave_min(ratio);
      if ((tid & 63) == 63) redD[tid >> 6] = wmn;
      __syncthreads();
      float mr = fminf(fminf(redD[0], redD[1]), fminf(redD[2], redD[3]));
      float kd = exact ? 0.9f : 0.99f;
      float t = fminf(1.f, kd * mr);
      if (act){
        y = fmaxf(fmaf(t, dy, y), 1e-12f);
        yv[row] = y;
        put_ph(phs, row, y);                     // repack y for next f16 use
      }
    }

    if (!exact && (gg <= P1_EXIT * gg0 || it + 1 >= N_PH1)) ph1done = true;
  }

  // ---- z = y / sum(y) (output 1) ----
  float wy = dpp_wave_sum(act ? y : 0.f);
  if ((tid & 63) == 63) red4[tid >> 6] = make_float4(wy, 0.f, 0.f, 0.f);
  __syncthreads();
  float ys = (red4[0].x + red4[1].x) + (red4[2].x + red4[3].x);
  if (act) out[(size_t)s * NA + row] = y / ys;
}

extern "C" void kernel_launch(void* const* d_in, const int* in_sizes, int n_in,
                              void* d_out, int out_size, void* d_ws, size_t ws_size,
                              hipStream_t stream) {
  const float* x     = (const float*)d_in[0];
  const float* Sigma = (const float*)d_in[1];
  const float* W1    = (const float*)d_in[2];
  const float* b1    = (const float*)d_in[3];
  const float* W2    = (const float*)d_in[4];
  const float* b2    = (const float*)d_in[5];
  float* out = (float*)d_out;
  hipLaunchKernelGGL(rb_kernel, dim3(B_SAMPLES), dim3(NTHREADS), 0, stream,
                     x, Sigma, W1, b1, W2, b2, out);
}

// Round 11
// 255.546 us; speedup vs baseline: 1.3310x; 1.3310x over previous
//
#include <hip/hip_runtime.h>
#include <math.h>

#define NF        128
#define H_DIM     256
#define NA        200
#define B_SAMPLES 512
#define ALPHA_LR  0.01f
#define B_MIN_C   1e-4f

#define NTHREADS  256               // 4 waves: thread t owns full row t (t<200)
#define ROWS_PER_WAVE 50            // exact-path: 4 waves x 50 rows

#define N_PH1     10
#define N_REFINE  1
#define CG_MAX    32                // exact-refinement CG cap (accuracy anchor)
#define CG_MAX_P1 16                // R11: phase-1 CG cap (tail truncation)
#define TOL2_LO   4e-4f             // refinement CG tolerance (accuracy anchor)
#define TOL2_P1   4e-3f             // phase-1 CG tolerance floor
#define TOL2_HI   6e-2f             // phase-1 CG tolerance cap
#define P1_FACT   8.f               // adaptive factor
#define P1_EXIT   1e-7f             // phase-1 Newton early-exit

typedef _Float16 h2_t __attribute__((ext_vector_type(2)));
typedef unsigned uv4  __attribute__((ext_vector_type(4)));

__device__ __forceinline__ h2_t as_h2(unsigned u){
  union { unsigned u; h2_t h; } c; c.u = u; return c.h;
}
__device__ __forceinline__ unsigned pk_f16(float a, float b){
#if __has_builtin(__builtin_amdgcn_cvt_pkrtz)
  union { decltype(__builtin_amdgcn_cvt_pkrtz(0.f, 0.f)) h; unsigned u; } c;
  c.h = __builtin_amdgcn_cvt_pkrtz(a, b);
  return c.u;
#else
  union { h2_t h; unsigned u; } c;
  c.h = (h2_t){ (_Float16)a, (_Float16)b };
  return c.u;
#endif
}
__device__ __forceinline__ float fdot2(unsigned m, unsigned v, float acc){
#if __has_builtin(__builtin_amdgcn_fdot2)
  return __builtin_amdgcn_fdot2(as_h2(m), as_h2(v), acc, false);
#else
  h2_t a = as_h2(m), b = as_h2(v);
  return fmaf((float)a.y, (float)b.y, fmaf((float)a.x, (float)b.x, acc));
#endif
}
// fast reciprocal (v_rcp_f32, ~1e-7 rel) for loop-carried scalar chain
__device__ __forceinline__ float fast_rcp(float x){
#if __has_builtin(__builtin_amdgcn_rcpf)
  return __builtin_amdgcn_rcpf(x);
#else
  return 1.f / x;
#endif
}

// ---------------- DPP wave-64 reductions (result valid in lane 63) --------
__device__ __forceinline__ float dpp_wave_sum(float v){
  v += __int_as_float(__builtin_amdgcn_update_dpp(0, __float_as_int(v), 0x111, 0xf, 0xf, false));
  v += __int_as_float(__builtin_amdgcn_update_dpp(0, __float_as_int(v), 0x112, 0xf, 0xf, false));
  v += __int_as_float(__builtin_amdgcn_update_dpp(0, __float_as_int(v), 0x114, 0xf, 0xf, false));
  v += __int_as_float(__builtin_amdgcn_update_dpp(0, __float_as_int(v), 0x118, 0xf, 0xf, false));
  v += __int_as_float(__builtin_amdgcn_update_dpp(0, __float_as_int(v), 0x142, 0xa, 0xf, false));
  v += __int_as_float(__builtin_amdgcn_update_dpp(0, __float_as_int(v), 0x143, 0xc, 0xf, false));
  return v;
}
__device__ __forceinline__ float dpp_wave_min(float v){
  const int PINF = 0x7f800000;
  v = fminf(v, __int_as_float(__builtin_amdgcn_update_dpp(PINF, __float_as_int(v), 0x111, 0xf, 0xf, false)));
  v = fminf(v, __int_as_float(__builtin_amdgcn_update_dpp(PINF, __float_as_int(v), 0x112, 0xf, 0xf, false)));
  v = fminf(v, __int_as_float(__builtin_amdgcn_update_dpp(PINF, __float_as_int(v), 0x114, 0xf, 0xf, false)));
  v = fminf(v, __int_as_float(__builtin_amdgcn_update_dpp(PINF, __float_as_int(v), 0x118, 0xf, 0xf, false)));
  v = fminf(v, __int_as_float(__builtin_amdgcn_update_dpp(PINF, __float_as_int(v), 0x142, 0xa, 0xf, false)));
  v = fminf(v, __int_as_float(__builtin_amdgcn_update_dpp(PINF, __float_as_int(v), 0x143, 0xc, 0xf, false)));
  return v;
}
__device__ __forceinline__ float dpp_wave_max(float v){
  const int NINF = 0xff800000;
  v = fmaxf(v, __int_as_float(__builtin_amdgcn_update_dpp(NINF, __float_as_int(v), 0x111, 0xf, 0xf, false)));
  v = fmaxf(v, __int_as_float(__builtin_amdgcn_update_dpp(NINF, __float_as_int(v), 0x112, 0xf, 0xf, false)));
  v = fmaxf(v, __int_as_float(__builtin_amdgcn_update_dpp(NINF, __float_as_int(v), 0x114, 0xf, 0xf, false)));
  v = fmaxf(v, __int_as_float(__builtin_amdgcn_update_dpp(NINF, __float_as_int(v), 0x118, 0xf, 0xf, false)));
  v = fmaxf(v, __int_as_float(__builtin_amdgcn_update_dpp(NINF, __float_as_int(v), 0x142, 0xa, 0xf, false)));
  v = fmaxf(v, __int_as_float(__builtin_amdgcn_update_dpp(NINF, __float_as_int(v), 0x143, 0xc, 0xf, false)));
  return v;
}
// block reductions over 4 waves (prologue only)
__device__ __forceinline__ float block_sum4(float v, float* red, int tid){
  __syncthreads();
  v = dpp_wave_sum(v);
  if ((tid & 63) == 63) red[tid >> 6] = v;
  __syncthreads();
  return (red[0] + red[1]) + (red[2] + red[3]);
}
__device__ __forceinline__ float block_max4(float v, float* red, int tid){
  __syncthreads();
  v = dpp_wave_max(v);
  if ((tid & 63) == 63) red[tid >> 6] = v;
  __syncthreads();
  return fmaxf(fmaxf(red[0], red[1]), fmaxf(red[2], red[3]));
}

// owner writes its f16 vector entry; returns the f16-rounded value actually
// stored (the matvec sees the rounded vector — needed so the S*y recurrence
// stays exactly consistent with the f16 operator)
__device__ __forceinline__ float put_ph2(unsigned short* phs, int row, float v){
  unsigned p = pk_f16(v, 0.f);
  phs[row] = (unsigned short)(p & 0xffffu);
  return (float)as_h2(p).x;
}

// packed-f16 full-row matvec: 100 dwords from VGPRs.
// Prefetch ALL 25 p-quads first (one LDS-latency exposure, not five).
__device__ __forceinline__ float mv_dot2(const unsigned* mreg,
                                         const unsigned* __restrict__ ph){
  const uv4* v4 = (const uv4*)ph;
  uv4 pv[25];
  #pragma unroll
  for (int k = 0; k < 25; ++k) pv[k] = v4[k];
  float a0=0.f, a1=0.f, a2=0.f, a3=0.f;
  #pragma unroll
  for (int k = 0; k < 25; ++k){
    a0 = fdot2(mreg[4*k+0], pv[k].x, a0);
    a1 = fdot2(mreg[4*k+1], pv[k].y, a1);
    a2 = fdot2(mreg[4*k+2], pv[k].z, a2);
    a3 = fdot2(mreg[4*k+3], pv[k].w, a3);
  }
  return (a0 + a1) + (a2 + a3);
}

// NO 2nd launch_bounds arg (R8: "(256,2)" clamps to 128 VGPR -> spill).
extern "C" __global__ __launch_bounds__(NTHREADS)
void rb_kernel(const float* __restrict__ x,  const float* __restrict__ Sigma,
               const float* __restrict__ W1, const float* __restrict__ b1,
               const float* __restrict__ W2, const float* __restrict__ b2,
               float* __restrict__ out) {
  __shared__ __align__(16) unsigned ph[100];          // packed f16 vector (200 h)
  __shared__ __align__(16) float yv[NA];
  __shared__ __align__(16) float partial[NA];
  __shared__ float xs[NF];
  __shared__ float hs[H_DIM];
  __shared__ __align__(16) float4 red4[4];            // fused CG reduction slots
  __shared__ float redD[4], red8[4];

  const int tid  = threadIdx.x;
  const int s    = blockIdx.x;
  const bool act = tid < NA;                          // thread t owns row t
  const int row  = tid;
  const float* S = Sigma + (size_t)s * NA * NA;
  unsigned short* phs = (unsigned short*)ph;

  if (tid < NF) xs[tid] = x[s * NF + tid];
  float sd = act ? S[(size_t)row * NA + row] : 0.f;

  // ---- stage Sigma row (packed f16): 100 dwords -> VGPRs ----
  unsigned mreg[100];
  if (act){
    const float4* rowp = (const float4*)(S + (size_t)row * NA);
    #pragma unroll
    for (int k = 0; k < 50; ++k){
      float4 w = rowp[k];
      mreg[2*k]   = pk_f16(w.x, w.y);
      mreg[2*k+1] = pk_f16(w.z, w.w);
    }
  }

  // ---- MLP ----
  __syncthreads();                        // xs visible
  {
    const float* w = W1 + tid * NF;       // tid < 256 == H_DIM
    float acc = b1[tid];
    #pragma unroll 8
    for (int j = 0; j < NF; ++j) acc = fmaf(w[j], xs[j], acc);
    hs[tid] = (acc >= 0.f) ? acc : ALPHA_LR * acc;
  }
  __syncthreads();
  float logit = -INFINITY;
  if (act){
    const float* w = W2 + row * H_DIM;
    float acc = b2[row];
    #pragma unroll 8
    for (int j = 0; j < H_DIM; ++j) acc = fmaf(w[j], hs[j], acc);
    logit = acc;
  }

  // ---- softmax -> b (output 2); clamp+renorm -> b_ (local, row==tid) ----
  float mx = block_max4(logit, red8, tid);
  float e  = act ? expf(logit - mx) : 0.f;
  float es = block_sum4(e, red8, tid);
  float bsoft = e / es;
  if (act) out[(size_t)B_SAMPLES * NA + (size_t)s * NA + row] = bsoft;
  float bcl = fmaxf(bsoft, B_MIN_C);
  float bs  = block_sum4(act ? bcl : 0.f, red8, tid);

  // Scale-matched init direction u_i = sqrt(b_i / S_ii) (R10): fixed point
  // satisfies y_i (S y)_i = b_i, so u matches per-coordinate scale.
  float b_ = 0.f, y = 0.f, q_run = 0.f, u0r = 0.f;
  if (act){
    b_  = bcl / bs;
    float u0 = sqrtf(b_ * fast_rcp(sd));
    u0r = put_ph2(phs, row, u0);          // f16-rounded init direction
  }

  // ---- y0 = f16(u) / sqrt(f16(u)^T S f16(u)); q_run = (S y0)_row ----
  // R11: q_run carries S*y through phase-1 via an exact recurrence — the
  // per-outer gradient matvec is eliminated.
  __syncthreads();                               // ph visible
  {
    float acc = act ? mv_dot2(mreg, ph) : 0.f;   // acc = (S_f16 * f16(u))_row
    float wq  = dpp_wave_sum(act ? u0r * acc : 0.f);
    if ((tid & 63) == 63) red4[tid >> 6] = make_float4(wq, 0.f, 0.f, 0.f);
    __syncthreads();
    float quad = (red4[0].x + red4[1].x) + (red4[2].x + red4[3].x);
    float rq = rsqrtf(quad);
    if (act){ y = u0r * rq; q_run = acc * rq; yv[row] = y; }
  }

  // ---- damped inexact Newton ----
  float gg0 = 1.f;
  bool  ph1done = false;
  int   nexact  = 0;
  for (int it = 0; it < N_PH1 + N_REFINE; ++it){
    if (nexact >= N_REFINE) break;
    const bool exact = ph1done;
    if (exact) ++nexact;

    // --- gradient: phase-1 uses the q_run recurrence (no matvec round);
    //     refinement recomputes exactly from global f32 ---
    if (exact){
      __syncthreads();                           // yv current, partial free
      int lane = tid & 63, wid = tid >> 6;
      int r0 = wid * ROWS_PER_WAVE;
      for (int rr = r0; rr < r0 + ROWS_PER_WAVE; ++rr){
        const float* rowp = S + (size_t)rr * NA;
        float a = rowp[lane]*yv[lane] + rowp[lane+64]*yv[lane+64]
                + rowp[lane+128]*yv[lane+128];
        if (lane < NA - 192) a += rowp[lane+192]*yv[lane+192];
        a = dpp_wave_sum(a);
        if (lane == 63) partial[rr] = a;
      }
      __syncthreads();
      if (act) q_run = partial[row];
    }
    // (phase-1: no barrier needed here — the previous outer's damped-step
    //  barrier already separates the last red4 read from the write below)

    // --- Newton init; reduce gg and rz together ---
    float g=0.f, d=0.f, mi=0.f;
    if (act){
      float ry = fast_rcp(y);
      g  = q_run - b_ * ry;
      d  = b_ * ry * ry;
      mi = fast_rcp(sd + d);
    }
    float wg = dpp_wave_sum(act ? g * g : 0.f);
    float wz = dpp_wave_sum(act ? g * g * mi : 0.f);   // rz = g^T M^-1 g
    if ((tid & 63) == 63) red4[tid >> 6] = make_float4(wg, wz, 0.f, 0.f);
    __syncthreads();
    float4 t0 = red4[0], t1 = red4[1], t2 = red4[2], t3 = red4[3];
    float gg = (t0.x + t1.x) + (t2.x + t3.x);
    float rz = (t0.y + t1.y) + (t2.y + t3.y);
    if (it == 0) gg0 = fmaxf(gg, 1e-30f);
    float tol2 = exact ? TOL2_LO
                       : fminf(TOL2_HI, fmaxf(TOL2_P1, P1_FACT * (gg / gg0)));

    if (gg > 1e-24f){
      // --- scale CG system by 1/||g|| so packed-f16 p never underflows ---
      const float cinv = rsqrtf(gg);
      const float csc  = sqrtf(gg);
      float r=0.f, z=0.f, dy=0.f, pj=0.f, pr=0.f, sdy=0.f;
      if (act){
        r  = -g * cinv;
        z  = mi * r;
        pj = z;
        pr = put_ph2(phs, row, pj);              // pr = f16(pj) the matvec sees
      }
      rz = rz * cinv * cinv;

      // --- Jacobi-PCG, fused single reduction (pq, rq, qq in one float4).
      // dy accumulates the f16-ROUNDED directions (pr) and sdy their images
      // S*pr (= qp), so q_run += t*sdy is exact for the f16 operator. ---
      const float rz0 = rz;
      const int jmax = exact ? CG_MAX : CG_MAX_P1;
      for (int j = 0; j < jmax; ++j){
        __syncthreads();                         // B1: ph visible, red4 reuse safe
        float qp = act ? mv_dot2(mreg, ph) : 0.f;
        float qf=0.f, cpq=0.f, crq=0.f, cqq=0.f;
        if (act){
          qf = qp + d * pj;
          float u = mi * qf;
          cpq = pj * qf; crq = r * u; cqq = qf * u;
        }
        cpq = dpp_wave_sum(cpq); crq = dpp_wave_sum(crq); cqq = dpp_wave_sum(cqq);
        if ((tid & 63) == 63) red4[tid >> 6] = make_float4(cpq, crq, cqq, 0.f);
        __syncthreads();                         // B2
        float4 w0 = red4[0], w1 = red4[1], w2 = red4[2], w3 = red4[3];
        float pq = (w0.x + w1.x) + (w2.x + w3.x);
        float rq = (w0.y + w1.y) + (w2.y + w3.y);
        float qq = (w0.z + w1.z) + (w2.z + w3.z);
        float alpha = rz * fast_rcp(pq);
        float rznew = fmaxf(fmaf(alpha*alpha, qq, fmaf(-2.f*alpha, rq, rz)), 0.f);
        if (act){
          dy  = fmaf(alpha, pr, dy);             // rounded direction
          sdy = fmaf(alpha, qp, sdy);            // its S-image
          r   = fmaf(-alpha, qf, r);
          z   = mi * r;
        }
        bool brk = (rznew <= tol2 * rz0) || (j == jmax - 1);
        if (!brk){
          float beta = rznew * fast_rcp(rz);
          if (act){ pj = fmaf(beta, pj, z); pr = put_ph2(phs, row, pj); }
        }
        rz = rznew;
        if (brk) break;
      }

      // --- unscale; damped step keeping y > 0. Phase-1 uses 0.99
      // fraction-to-boundary; exact refinement keeps reference 0.9. ---
      if (act){ dy *= csc; sdy *= csc; }
      float ratio = (act && dy < 0.f) ? (-y / dy) : 1e30f;
      float wmn = dpp_wave_min(ratio);
      if ((tid & 63) == 63) redD[tid >> 6] = wmn;
      __syncthreads();
      float mr = fminf(fminf(redD[0], redD[1]), fminf(redD[2], redD[3]));
      float kd = exact ? 0.9f : 0.99f;
      float t = fminf(1.f, kd * mr);
      if (act){
        y = fmaxf(fmaf(t, dy, y), 1e-12f);
        yv[row] = y;
        q_run = fmaf(t, sdy, q_run);             // S*y recurrence
      }
    }

    if (!exact && (gg <= P1_EXIT * gg0 || it + 1 >= N_PH1)) ph1done = true;
  }

  // ---- z = y / sum(y) (output 1) ----
  float wy = dpp_wave_sum(act ? y : 0.f);
  if ((tid & 63) == 63) red4[tid >> 6] = make_float4(wy, 0.f, 0.f, 0.f);
  __syncthreads();
  float ys = (red4[0].x + red4[1].x) + (red4[2].x + red4[3].x);
  if (act) out[(size_t)s * NA + row] = y / ys;
}

extern "C" void kernel_launch(void* const* d_in, const int* in_sizes, int n_in,
                              void* d_out, int out_size, void* d_ws, size_t ws_size,
                              hipStream_t stream) {
  const float* x     = (const float*)d_in[0];
  const float* Sigma = (const float*)d_in[1];
  const float* W1    = (const float*)d_in[2];
  const float* b1    = (const float*)d_in[3];
  const float* W2    = (const float*)d_in[4];
  const float* b2    = (const float*)d_in[5];
  float* out = (float*)d_out;
  hipLaunchKernelGGL(rb_kernel, dim3(B_SAMPLES), dim3(NTHREADS), 0, stream,
                     x, Sigma, W1, b1, W2, b2, out);
}

// Round 12
// 233.764 us; speedup vs baseline: 1.4550x; 1.0932x over previous
//
#include <hip/hip_runtime.h>
#include <math.h>

#define NF        128
#define H_DIM     256
#define NA        200
#define B_SAMPLES 512
#define ALPHA_LR  0.01f
#define B_MIN_C   1e-4f

#define NTHREADS  256               // 4 waves: thread t owns full row t (t<200)
#define ROWS_PER_WAVE 50            // exact-path: 4 waves x 50 rows

#define N_PH1     8                 // R12: phase-1 outer cap (was 10; tail hit it)
#define N_REFINE  1
#define CG_MAX    32                // exact-refinement CG cap
#define CG_MAX_P1 12                // R12: phase-1 CG cap (was 16; tail hit it)
#define TOL2_LO   1.6e-3f           // R12: refinement CG tol (was 4e-4; one
                                    // inexact-Newton step contracts rel-err to
                                    // ~tol*delta ~ 1e-5 — z stays ~1e-6 abs)
#define TOL2_P1   4e-3f             // phase-1 CG tolerance floor
#define TOL2_HI   6e-2f             // phase-1 CG tolerance cap
#define P1_FACT   8.f               // adaptive factor
#define P1_EXIT   1e-7f             // phase-1 Newton early-exit

typedef _Float16 h2_t __attribute__((ext_vector_type(2)));
typedef unsigned uv4  __attribute__((ext_vector_type(4)));

__device__ __forceinline__ h2_t as_h2(unsigned u){
  union { unsigned u; h2_t h; } c; c.u = u; return c.h;
}
__device__ __forceinline__ unsigned pk_f16(float a, float b){
#if __has_builtin(__builtin_amdgcn_cvt_pkrtz)
  union { decltype(__builtin_amdgcn_cvt_pkrtz(0.f, 0.f)) h; unsigned u; } c;
  c.h = __builtin_amdgcn_cvt_pkrtz(a, b);
  return c.u;
#else
  union { h2_t h; unsigned u; } c;
  c.h = (h2_t){ (_Float16)a, (_Float16)b };
  return c.u;
#endif
}
__device__ __forceinline__ float fdot2(unsigned m, unsigned v, float acc){
#if __has_builtin(__builtin_amdgcn_fdot2)
  return __builtin_amdgcn_fdot2(as_h2(m), as_h2(v), acc, false);
#else
  h2_t a = as_h2(m), b = as_h2(v);
  return fmaf((float)a.y, (float)b.y, fmaf((float)a.x, (float)b.x, acc));
#endif
}
// fast reciprocal (v_rcp_f32, ~1e-7 rel) for loop-carried scalar chain
__device__ __forceinline__ float fast_rcp(float x){
#if __has_builtin(__builtin_amdgcn_rcpf)
  return __builtin_amdgcn_rcpf(x);
#else
  return 1.f / x;
#endif
}

// ---------------- DPP wave-64 reductions (result valid in lane 63) --------
__device__ __forceinline__ float dpp_wave_sum(float v){
  v += __int_as_float(__builtin_amdgcn_update_dpp(0, __float_as_int(v), 0x111, 0xf, 0xf, false));
  v += __int_as_float(__builtin_amdgcn_update_dpp(0, __float_as_int(v), 0x112, 0xf, 0xf, false));
  v += __int_as_float(__builtin_amdgcn_update_dpp(0, __float_as_int(v), 0x114, 0xf, 0xf, false));
  v += __int_as_float(__builtin_amdgcn_update_dpp(0, __float_as_int(v), 0x118, 0xf, 0xf, false));
  v += __int_as_float(__builtin_amdgcn_update_dpp(0, __float_as_int(v), 0x142, 0xa, 0xf, false));
  v += __int_as_float(__builtin_amdgcn_update_dpp(0, __float_as_int(v), 0x143, 0xc, 0xf, false));
  return v;
}
__device__ __forceinline__ float dpp_wave_min(float v){
  const int PINF = 0x7f800000;
  v = fminf(v, __int_as_float(__builtin_amdgcn_update_dpp(PINF, __float_as_int(v), 0x111, 0xf, 0xf, false)));
  v = fminf(v, __int_as_float(__builtin_amdgcn_update_dpp(PINF, __float_as_int(v), 0x112, 0xf, 0xf, false)));
  v = fminf(v, __int_as_float(__builtin_amdgcn_update_dpp(PINF, __float_as_int(v), 0x114, 0xf, 0xf, false)));
  v = fminf(v, __int_as_float(__builtin_amdgcn_update_dpp(PINF, __float_as_int(v), 0x118, 0xf, 0xf, false)));
  v = fminf(v, __int_as_float(__builtin_amdgcn_update_dpp(PINF, __float_as_int(v), 0x142, 0xa, 0xf, false)));
  v = fminf(v, __int_as_float(__builtin_amdgcn_update_dpp(PINF, __float_as_int(v), 0x143, 0xc, 0xf, false)));
  return v;
}
__device__ __forceinline__ float dpp_wave_max(float v){
  const int NINF = 0xff800000;
  v = fmaxf(v, __int_as_float(__builtin_amdgcn_update_dpp(NINF, __float_as_int(v), 0x111, 0xf, 0xf, false)));
  v = fmaxf(v, __int_as_float(__builtin_amdgcn_update_dpp(NINF, __float_as_int(v), 0x112, 0xf, 0xf, false)));
  v = fmaxf(v, __int_as_float(__builtin_amdgcn_update_dpp(NINF, __float_as_int(v), 0x114, 0xf, 0xf, false)));
  v = fmaxf(v, __int_as_float(__builtin_amdgcn_update_dpp(NINF, __float_as_int(v), 0x118, 0xf, 0xf, false)));
  v = fmaxf(v, __int_as_float(__builtin_amdgcn_update_dpp(NINF, __float_as_int(v), 0x142, 0xa, 0xf, false)));
  v = fmaxf(v, __int_as_float(__builtin_amdgcn_update_dpp(NINF, __float_as_int(v), 0x143, 0xc, 0xf, false)));
  return v;
}
// block reductions over 4 waves (prologue only)
__device__ __forceinline__ float block_sum4(float v, float* red, int tid){
  __syncthreads();
  v = dpp_wave_sum(v);
  if ((tid & 63) == 63) red[tid >> 6] = v;
  __syncthreads();
  return (red[0] + red[1]) + (red[2] + red[3]);
}
__device__ __forceinline__ float block_max4(float v, float* red, int tid){
  __syncthreads();
  v = dpp_wave_max(v);
  if ((tid & 63) == 63) red[tid >> 6] = v;
  __syncthreads();
  return fmaxf(fmaxf(red[0], red[1]), fmaxf(red[2], red[3]));
}

// owner writes its f16 vector entry; returns the f16-rounded value actually
// stored (the matvec sees the rounded vector — needed so the S*y recurrence
// stays exactly consistent with the f16 operator)
__device__ __forceinline__ float put_ph2(unsigned short* phs, int row, float v){
  unsigned p = pk_f16(v, 0.f);
  phs[row] = (unsigned short)(p & 0xffffu);
  return (float)as_h2(p).x;
}

// packed-f16 full-row matvec: 100 dwords from VGPRs.
// Prefetch ALL 25 p-quads first (one LDS-latency exposure, not five).
__device__ __forceinline__ float mv_dot2(const unsigned* mreg,
                                         const unsigned* __restrict__ ph){
  const uv4* v4 = (const uv4*)ph;
  uv4 pv[25];
  #pragma unroll
  for (int k = 0; k < 25; ++k) pv[k] = v4[k];
  float a0=0.f, a1=0.f, a2=0.f, a3=0.f;
  #pragma unroll
  for (int k = 0; k < 25; ++k){
    a0 = fdot2(mreg[4*k+0], pv[k].x, a0);
    a1 = fdot2(mreg[4*k+1], pv[k].y, a1);
    a2 = fdot2(mreg[4*k+2], pv[k].z, a2);
    a3 = fdot2(mreg[4*k+3], pv[k].w, a3);
  }
  return (a0 + a1) + (a2 + a3);
}

// NO 2nd launch_bounds arg (R8: "(256,2)" clamps to 128 VGPR -> spill).
extern "C" __global__ __launch_bounds__(NTHREADS)
void rb_kernel(const float* __restrict__ x,  const float* __restrict__ Sigma,
               const float* __restrict__ W1, const float* __restrict__ b1,
               const float* __restrict__ W2, const float* __restrict__ b2,
               float* __restrict__ out) {
  __shared__ __align__(16) unsigned ph[100];          // packed f16 vector (200 h)
  __shared__ __align__(16) float yv[NA];
  __shared__ __align__(16) float partial[NA];
  __shared__ float xs[NF];
  __shared__ float hs[H_DIM];
  __shared__ __align__(16) float4 red4[4];            // fused CG reduction slots
  __shared__ float redD[4], red8[4];

  const int tid  = threadIdx.x;
  const int s    = blockIdx.x;
  const bool act = tid < NA;                          // thread t owns row t
  const int row  = tid;
  const float* S = Sigma + (size_t)s * NA * NA;
  unsigned short* phs = (unsigned short*)ph;

  if (tid < NF) xs[tid] = x[s * NF + tid];
  float sd = act ? S[(size_t)row * NA + row] : 0.f;

  // ---- stage Sigma row (packed f16): 100 dwords -> VGPRs ----
  unsigned mreg[100];
  if (act){
    const float4* rowp = (const float4*)(S + (size_t)row * NA);
    #pragma unroll
    for (int k = 0; k < 50; ++k){
      float4 w = rowp[k];
      mreg[2*k]   = pk_f16(w.x, w.y);
      mreg[2*k+1] = pk_f16(w.z, w.w);
    }
  }

  // ---- MLP ----
  __syncthreads();                        // xs visible
  {
    const float* w = W1 + tid * NF;       // tid < 256 == H_DIM
    float acc = b1[tid];
    #pragma unroll 8
    for (int j = 0; j < NF; ++j) acc = fmaf(w[j], xs[j], acc);
    hs[tid] = (acc >= 0.f) ? acc : ALPHA_LR * acc;
  }
  __syncthreads();
  float logit = -INFINITY;
  if (act){
    const float* w = W2 + row * H_DIM;
    float acc = b2[row];
    #pragma unroll 8
    for (int j = 0; j < H_DIM; ++j) acc = fmaf(w[j], hs[j], acc);
    logit = acc;
  }

  // ---- softmax -> b (output 2); clamp+renorm -> b_ (local, row==tid) ----
  float mx = block_max4(logit, red8, tid);
  float e  = act ? expf(logit - mx) : 0.f;
  float es = block_sum4(e, red8, tid);
  float bsoft = e / es;
  if (act) out[(size_t)B_SAMPLES * NA + (size_t)s * NA + row] = bsoft;
  float bcl = fmaxf(bsoft, B_MIN_C);
  float bs  = block_sum4(act ? bcl : 0.f, red8, tid);

  // Scale-matched init direction u_i = sqrt(b_i / S_ii) (R10): fixed point
  // satisfies y_i (S y)_i = b_i, so u matches per-coordinate scale.
  float b_ = 0.f, y = 0.f, q_run = 0.f, u0r = 0.f;
  if (act){
    b_  = bcl / bs;
    float u0 = sqrtf(b_ * fast_rcp(sd));
    u0r = put_ph2(phs, row, u0);          // f16-rounded init direction
  }

  // ---- y0 = f16(u) / sqrt(f16(u)^T S f16(u)); q_run = (S y0)_row ----
  // q_run carries S*y through phase-1 via an exact recurrence (R11) — the
  // per-outer gradient matvec is eliminated.
  __syncthreads();                               // ph visible
  {
    float acc = act ? mv_dot2(mreg, ph) : 0.f;   // acc = (S_f16 * f16(u))_row
    float wq  = dpp_wave_sum(act ? u0r * acc : 0.f);
    if ((tid & 63) == 63) red4[tid >> 6] = make_float4(wq, 0.f, 0.f, 0.f);
    __syncthreads();
    float quad = (red4[0].x + red4[1].x) + (red4[2].x + red4[3].x);
    float rq = rsqrtf(quad);
    if (act){ y = u0r * rq; q_run = acc * rq; yv[row] = y; }
  }

  // ---- damped inexact Newton ----
  float gg0 = 1.f;
  bool  ph1done = false;
  int   nexact  = 0;
  for (int it = 0; it < N_PH1 + N_REFINE; ++it){
    if (nexact >= N_REFINE) break;
    const bool exact = ph1done;
    if (exact) ++nexact;

    // --- gradient: phase-1 uses the q_run recurrence (no matvec round);
    //     refinement recomputes exactly from global f32 ---
    if (exact){
      __syncthreads();                           // yv current, partial free
      int lane = tid & 63, wid = tid >> 6;
      int r0 = wid * ROWS_PER_WAVE;
      for (int rr = r0; rr < r0 + ROWS_PER_WAVE; ++rr){
        const float* rowp = S + (size_t)rr * NA;
        float a = rowp[lane]*yv[lane] + rowp[lane+64]*yv[lane+64]
                + rowp[lane+128]*yv[lane+128];
        if (lane < NA - 192) a += rowp[lane+192]*yv[lane+192];
        a = dpp_wave_sum(a);
        if (lane == 63) partial[rr] = a;
      }
      __syncthreads();
      if (act) q_run = partial[row];
    }

    // --- Newton init; reduce gg and rz together ---
    float g=0.f, d=0.f, mi=0.f;
    if (act){
      float ry = fast_rcp(y);
      g  = q_run - b_ * ry;
      d  = b_ * ry * ry;
      mi = fast_rcp(sd + d);
    }
    float wg = dpp_wave_sum(act ? g * g : 0.f);
    float wz = dpp_wave_sum(act ? g * g * mi : 0.f);   // rz = g^T M^-1 g
    if ((tid & 63) == 63) red4[tid >> 6] = make_float4(wg, wz, 0.f, 0.f);
    __syncthreads();
    float4 t0 = red4[0], t1 = red4[1], t2 = red4[2], t3 = red4[3];
    float gg = (t0.x + t1.x) + (t2.x + t3.x);
    float rz = (t0.y + t1.y) + (t2.y + t3.y);
    if (it == 0) gg0 = fmaxf(gg, 1e-30f);
    float tol2 = exact ? TOL2_LO
                       : fminf(TOL2_HI, fmaxf(TOL2_P1, P1_FACT * (gg / gg0)));

    if (gg > 1e-24f){
      // --- scale CG system by 1/||g|| so packed-f16 p never underflows ---
      const float cinv = rsqrtf(gg);
      const float csc  = sqrtf(gg);
      float r=0.f, z=0.f, dy=0.f, pj=0.f, pr=0.f, sdy=0.f;
      if (act){
        r  = -g * cinv;
        z  = mi * r;
        pj = z;
        pr = put_ph2(phs, row, pj);              // pr = f16(pj) the matvec sees
      }
      rz = rz * cinv * cinv;

      // --- Jacobi-PCG, fused single reduction (pq, rq, qq in one float4).
      // dy accumulates the f16-ROUNDED directions (pr) and sdy their images
      // S*pr (= qp), so q_run += t*sdy is exact for the f16 operator. ---
      const float rz0 = rz;
      const int jmax = exact ? CG_MAX : CG_MAX_P1;
      for (int j = 0; j < jmax; ++j){
        __syncthreads();                         // B1: ph visible, red4 reuse safe
        float qp = act ? mv_dot2(mreg, ph) : 0.f;
        float qf=0.f, cpq=0.f, crq=0.f, cqq=0.f;
        if (act){
          qf = qp + d * pj;
          float u = mi * qf;
          cpq = pj * qf; crq = r * u; cqq = qf * u;
        }
        cpq = dpp_wave_sum(cpq); crq = dpp_wave_sum(crq); cqq = dpp_wave_sum(cqq);
        if ((tid & 63) == 63) red4[tid >> 6] = make_float4(cpq, crq, cqq, 0.f);
        __syncthreads();                         // B2
        float4 w0 = red4[0], w1 = red4[1], w2 = red4[2], w3 = red4[3];
        float pq = (w0.x + w1.x) + (w2.x + w3.x);
        float rq = (w0.y + w1.y) + (w2.y + w3.y);
        float qq = (w0.z + w1.z) + (w2.z + w3.z);
        float alpha = rz * fast_rcp(pq);
        float rznew = fmaxf(fmaf(alpha*alpha, qq, fmaf(-2.f*alpha, rq, rz)), 0.f);
        if (act){
          dy  = fmaf(alpha, pr, dy);             // rounded direction
          sdy = fmaf(alpha, qp, sdy);            // its S-image
          r   = fmaf(-alpha, qf, r);
          z   = mi * r;
        }
        bool brk = (rznew <= tol2 * rz0) || (j == jmax - 1);
        if (!brk){
          float beta = rznew * fast_rcp(rz);
          if (act){ pj = fmaf(beta, pj, z); pr = put_ph2(phs, row, pj); }
        }
        rz = rznew;
        if (brk) break;
      }

      // --- unscale; damped step keeping y > 0. Phase-1 uses 0.99
      // fraction-to-boundary; exact refinement keeps reference 0.9. ---
      if (act){ dy *= csc; sdy *= csc; }
      float ratio = (act && dy < 0.f) ? (-y / dy) : 1e30f;
      float wmn = dpp_wave_min(ratio);
      if ((tid & 63) == 63) redD[tid >> 6] = wmn;
      __syncthreads();
      float mr = fminf(fminf(redD[0], redD[1]), fminf(redD[2], redD[3]));
      float kd = exact ? 0.9f : 0.99f;
      float t = fminf(1.f, kd * mr);
      if (act){
        y = fmaxf(fmaf(t, dy, y), 1e-12f);
        yv[row] = y;
        q_run = fmaf(t, sdy, q_run);             // S*y recurrence
      }
    }

    if (!exact && (gg <= P1_EXIT * gg0 || it + 1 >= N_PH1)) ph1done = true;
  }

  // ---- z = y / sum(y) (output 1) ----
  float wy = dpp_wave_sum(act ? y : 0.f);
  if ((tid & 63) == 63) red4[tid >> 6] = make_float4(wy, 0.f, 0.f, 0.f);
  __syncthreads();
  float ys = (red4[0].x + red4[1].x) + (red4[2].x + red4[3].x);
  if (act) out[(size_t)s * NA + row] = y / ys;
}

extern "C" void kernel_launch(void* const* d_in, const int* in_sizes, int n_in,
                              void* d_out, int out_size, void* d_ws, size_t ws_size,
                              hipStream_t stream) {
  const float* x     = (const float*)d_in[0];
  const float* Sigma = (const float*)d_in[1];
  const float* W1    = (const float*)d_in[2];
  const float* b1    = (const float*)d_in[3];
  const float* W2    = (const float*)d_in[4];
  const float* b2    = (const float*)d_in[5];
  float* out = (float*)d_out;
  hipLaunchKernelGGL(rb_kernel, dim3(B_SAMPLES), dim3(NTHREADS), 0, stream,
                     x, Sigma, W1, b1, W2, b2, out);
}